// Round 2
// baseline (587.643 us; speedup 1.0000x reference)
//
#include <hip/hip_runtime.h>

#define BB 1024
#define TT 512
#define KK 64

// ---- wave(64)-wide reductions via butterfly shuffles (used only in tails) ----
__device__ __forceinline__ float wmaxf(float x) {
#pragma unroll
  for (int off = 32; off > 0; off >>= 1) x = fmaxf(x, __shfl_xor(x, off, 64));
  return x;
}
__device__ __forceinline__ float wsumf(float x) {
#pragma unroll
  for (int off = 32; off > 0; off >>= 1) x += __shfl_xor(x, off, 64);
  return x;
}

// One block = one batch element. 128 threads = 2 waves:
//   wave0: forward algorithm (logZ) + gold score -> nll = logZ - gold
//   wave1: viterbi recurrence (bp in LDS) + backtrace -> path
// The two waves touch disjoint LDS buffers and never synchronize.
extern "C" __global__ void __launch_bounds__(128, 2) crf_all_kernel(
    const float* __restrict__ em,      // [B,T,K]
    const int* __restrict__ tags,      // [B,T]
    const int* __restrict__ mask,      // [B,T]
    const float* __restrict__ trans,   // [K,K]
    const float* __restrict__ startt,  // [K]
    const float* __restrict__ endt,    // [K]
    float* __restrict__ out) {         // [B] nll ++ [B,T] path (as float)
  __shared__ unsigned char bp[(TT - 1) * KK];     // 32704 B backpointers
  __shared__ __align__(16) float pbuf[KK];        // forward exp(alpha-M)
  __shared__ __align__(16) float vbuf[KK];        // viterbi v broadcast

  const int b = blockIdx.x;
  const int lane = threadIdx.x & 63;
  const float* emb = em + (size_t)b * TT * KK;
  const int* maskb = mask + b * TT;
  const int* tagsb = tags + b * TT;

  // Pre-ballot all 512 mask bits into 8 wave-uniform u64s: per-step mask
  // becomes pure scalar ALU (no memory in the recurrence loops).
  unsigned long long mb[8];
#pragma unroll
  for (int u = 0; u < 8; ++u) mb[u] = __ballot(maskb[u * KK + lane] != 0);

  if (threadIdx.x < 64) {
    // ---------------- wave0: forward (logZ) + gold score ----------------
    // lane j holds column j of E = exp(trans): E[i][j] over i, in registers.
    float Ecol[KK];
#pragma unroll
    for (int i = 0; i < KK; ++i) Ecol[i] = __expf(trans[i * KK + lane]);

    float alpha = startt[lane] + emb[lane];
    float emv = emb[KK + lane];  // t = 1, prefetched
    int t = 1;
#pragma unroll 1
    for (int u = 0; u < 8; ++u) {
      unsigned long long um = mb[u];
      int s = 0;
      if (u == 0) { um >>= 1; s = 1; }
#pragma unroll 1
      for (; s < 64; ++s, ++t) {
        const int m = (int)(um & 1ull);
        um >>= 1;
        // prefetch next step's emissions (clamped at the end)
        float emv_n = emb[(t < TT - 1 ? t + 1 : TT - 1) * KK + lane];
        // Stabilization point: ANY in-range M works; lane0's alpha avoids the
        // 6-stage shuffle chain. Cross-lane alpha spread is ~±4 here.
        float M = __int_as_float(__builtin_amdgcn_readfirstlane(__float_as_int(alpha)));
        pbuf[lane] = __expf(alpha - M);
        __builtin_amdgcn_wave_barrier();  // same-wave LDS in-order; fence compiler
        float s0 = 0.f, s1 = 0.f, s2 = 0.f, s3 = 0.f;
#pragma unroll
        for (int i = 0; i < KK; i += 4) {
          float4 pv = *(const float4*)&pbuf[i];  // same-address broadcast ds_read_b128
          s0 = fmaf(pv.x, Ecol[i + 0], s0);
          s1 = fmaf(pv.y, Ecol[i + 1], s1);
          s2 = fmaf(pv.z, Ecol[i + 2], s2);
          s3 = fmaf(pv.w, Ecol[i + 3], s3);
        }
        __builtin_amdgcn_wave_barrier();
        float na = __logf((s0 + s1) + (s2 + s3)) + M + emv;
        alpha = (m != 0) ? na : alpha;
        emv = emv_n;
      }
    }
    // logZ = logsumexp(alpha + end) — exact max here (runs once)
    float x = alpha + endt[lane];
    float M2 = wmaxf(x);
    float S = wsumf(__expf(x - M2));
    float logZ = __logf(S) + M2;

    // gold score: lane j covers t = u*64 + j; mask from mb bits
    float acc = 0.f;
#pragma unroll
    for (int u = 0; u < TT / KK; ++u) {
      int t2 = u * KK + lane;
      int tg = tagsb[t2];
      float mf = (float)((mb[u] >> lane) & 1ull);
      acc = fmaf(emb[t2 * KK + tg], mf, acc);
      if (t2 >= 1) acc = fmaf(trans[tagsb[t2 - 1] * KK + tg], mf, acc);
    }
    acc = wsumf(acc);
    int msum = 0;
#pragma unroll
    for (int u = 0; u < 8; ++u) msum += __popcll(mb[u]);
    if (lane == 0) {
      float gold = acc + startt[tagsb[0]] + endt[tagsb[msum - 1]];
      out[b] = logZ - gold;
    }
  } else {
    // ---------------- wave1: viterbi + backtrace ----------------
    // lane j holds column j of trans in registers.
    float Tcol[KK];
#pragma unroll
    for (int i = 0; i < KK; ++i) Tcol[i] = trans[i * KK + lane];

    float v = startt[lane] + emb[lane];
    float emv = emb[KK + lane];  // t = 1, prefetched
    int t = 1;
#pragma unroll 1
    for (int u = 0; u < 8; ++u) {
      unsigned long long um = mb[u];
      int s = 0;
      if (u == 0) { um >>= 1; s = 1; }
#pragma unroll 1
      for (; s < 64; ++s, ++t) {
        const int m = (int)(um & 1ull);
        um >>= 1;
        float emv_n = emb[(t < TT - 1 ? t + 1 : TT - 1) * KK + lane];
        vbuf[lane] = v;
        __builtin_amdgcn_wave_barrier();
        // Pass 1: scores into registers (exact fp32 adds, matches reference).
        float c[KK];
#pragma unroll
        for (int i = 0; i < KK; i += 4) {
          float4 vv = *(const float4*)&vbuf[i];  // broadcast
          c[i + 0] = vv.x + Tcol[i + 0];
          c[i + 1] = vv.y + Tcol[i + 1];
          c[i + 2] = vv.z + Tcol[i + 2];
          c[i + 3] = vv.w + Tcol[i + 3];
        }
        __builtin_amdgcn_wave_barrier();
        // Pass 2: value max (associative, bit-exact) via 4 independent chains.
        float b0 = c[0], b1 = c[1], b2 = c[2], b3 = c[3];
#pragma unroll
        for (int i = 4; i < KK; i += 4) {
          b0 = fmaxf(b0, c[i + 0]);
          b1 = fmaxf(b1, c[i + 1]);
          b2 = fmaxf(b2, c[i + 2]);
          b3 = fmaxf(b3, c[i + 3]);
        }
        float best = fmaxf(fmaxf(b0, b1), fmaxf(b2, b3));
        // Pass 3: first index achieving the max (descending eq-scan ->
        // smallest tied index == np.argmax semantics).
        int bi = 63;
#pragma unroll
        for (int i = 62; i >= 0; --i) bi = (c[i] == best) ? i : bi;
        bp[(t - 1) * KK + lane] = (unsigned char)((m != 0) ? bi : lane);
        v = (m != 0) ? (best + emv) : v;
        emv = emv_n;
      }
    }
    // last = argmax(v + end), first-index on exact ties
    float sc = v + endt[lane];
    int idx = lane;
#pragma unroll
    for (int off = 32; off > 0; off >>= 1) {
      float osc = __shfl_xor(sc, off, 64);
      int oidx = __shfl_xor(idx, off, 64);
      if (osc > sc || (osc == sc && oidx < idx)) { sc = osc; idx = oidx; }
    }
    // backtrace: all lanes follow the same chain (uniform broadcast reads)
    int tag = idx;
    float* pout = out + BB + (size_t)b * TT;
    for (int tt = TT - 1; tt >= 1; --tt) {
      if (lane == 0) pout[tt] = (float)tag;
      tag = bp[(tt - 1) * KK + tag];
    }
    if (lane == 0) pout[0] = (float)tag;
  }
}

extern "C" void kernel_launch(void* const* d_in, const int* in_sizes, int n_in,
                              void* d_out, int out_size, void* d_ws, size_t ws_size,
                              hipStream_t stream) {
  (void)in_sizes; (void)n_in; (void)out_size; (void)d_ws; (void)ws_size;
  const float* em = (const float*)d_in[0];
  const int* tags = (const int*)d_in[1];
  const int* mask = (const int*)d_in[2];
  const float* trans = (const float*)d_in[3];
  const float* startt = (const float*)d_in[4];
  const float* endt = (const float*)d_in[5];
  float* out = (float*)d_out;
  crf_all_kernel<<<dim3(BB), dim3(128), 0, stream>>>(em, tags, mask, trans,
                                                     startt, endt, out);
}